// Round 1
// baseline (1141.327 us; speedup 1.0000x reference)
//
#include <hip/hip_runtime.h>

// ---------------------------------------------------------------------------
// MR_GNN: 2x (RGCN + GroupEnhance) + linear head.
// Strategy: relation-bucketed scatter (edge side, atomics) + node-side GEMMs.
//   agg[v] = sum_r (sum_{e:r,dst=v} w_e x[src_e]) @ W[r]
// so the E*64*64 per-edge matmuls collapse to N-side [N x 320]@[320 x 64].
// ---------------------------------------------------------------------------

__global__ void deg_count(const int* __restrict__ ei, float* __restrict__ deg, int E) {
    int e = blockIdx.x * blockDim.x + threadIdx.x;
    if (e < E) unsafeAtomicAdd(&deg[ei[E + e]], 1.0f);
}

// one wave (64 lanes = 64 features) per edge; 4 edges per block
__global__ void scatter_rel(const float* __restrict__ X, const int* __restrict__ ei,
                            const int* __restrict__ et, const float* __restrict__ ew,
                            float* __restrict__ aggR, int E) {
    int e = blockIdx.x * 4 + (threadIdx.x >> 6);
    if (e >= E) return;
    int lane = threadIdx.x & 63;
    int s = ei[e];
    int d = ei[E + e];
    int r = et[e];
    float w = ew[e];
    float v = w * X[(size_t)s * 64 + lane];
    unsafeAtomicAdd(&aggR[(size_t)d * 256 + r * 64 + lane], v);
}

__global__ void scatter_plain(const float* __restrict__ H, const int* __restrict__ ei,
                              const float* __restrict__ ew,
                              float* __restrict__ agg, int E) {
    int e = blockIdx.x * 4 + (threadIdx.x >> 6);
    if (e >= E) return;
    int lane = threadIdx.x & 63;
    int s = ei[e];
    int d = ei[E + e];
    float w = ew[e];
    unsafeAtomicAdd(&agg[(size_t)d * 64 + lane], w * H[(size_t)s * 64 + lane]);
}

// ---------------------------------------------------------------------------
// Node-side tiled GEMM. BM=64 rows x 64 cols per block, 256 threads,
// 4x4 micro-tile per thread. K is chunked in units of 64.
// MODE 0 (rgcn):  OUT = relu((X@B0 + AGG@B1) / deg)        OUT: N x 64
// MODE 1 (group): OUT = X + alpha*((AGG@B0)/deg + bias)    OUT: N x 64
// MODE 2 (head):  OUT = X@B0 + bias                        OUT: N x 32
// ---------------------------------------------------------------------------
template <int MODE>
__global__ __launch_bounds__(256) void node_gemm(
    const float* __restrict__ X, const float* __restrict__ AGG,
    const float* __restrict__ B0, const float* __restrict__ B1,
    const float* __restrict__ bias, const float* __restrict__ alphap,
    const float* __restrict__ deg, float* __restrict__ OUT, int N) {
    __shared__ float As[64][68];   // stride 68: float4-aligned rows, 2-way banks (free)
    __shared__ float Bs[64][64];
    const int tid = threadIdx.x;
    const int tx = tid & 15, ty = tid >> 4;
    const int row0 = blockIdx.x * 64;
    float acc[4][4] = {};

    const int nchunks = (MODE == 0) ? 5 : 1;
    for (int c = 0; c < nchunks; ++c) {
        const float* A;
        int lda;
        const float* B;
        int ldb, bcols;
        if (MODE == 0) {
            if (c == 0) { A = X; lda = 64; B = B0; }
            else        { A = AGG + (c - 1) * 64; lda = 256; B = B1 + (size_t)(c - 1) * 64 * 64; }
            ldb = 64; bcols = 64;
        } else if (MODE == 1) {
            A = AGG; lda = 64; B = B0; ldb = 64; bcols = 64;
        } else {
            A = X; lda = 64; B = B0; ldb = 32; bcols = 32;
        }
        if (c) __syncthreads();  // protect LDS reuse against previous chunk's readers
#pragma unroll
        for (int q = 0; q < 4; ++q) {
            int f = q * 256 + tid;           // 0..1023
            int r = f >> 4;                  // 0..63
            int c4 = (f & 15) << 2;          // 0..60
            float4 v = make_float4(0.f, 0.f, 0.f, 0.f);
            int vr = row0 + r;
            if (vr < N) v = *reinterpret_cast<const float4*>(A + (size_t)vr * lda + c4);
            *reinterpret_cast<float4*>(&As[r][c4]) = v;
            float4 bv = make_float4(0.f, 0.f, 0.f, 0.f);
            if (c4 < bcols) bv = *reinterpret_cast<const float4*>(B + (size_t)r * ldb + c4);
            *reinterpret_cast<float4*>(&Bs[r][c4]) = bv;
        }
        __syncthreads();
#pragma unroll 8
        for (int k = 0; k < 64; ++k) {
            float4 b = *reinterpret_cast<const float4*>(&Bs[k][tx * 4]);
            float a0 = As[ty * 4 + 0][k];
            float a1 = As[ty * 4 + 1][k];
            float a2 = As[ty * 4 + 2][k];
            float a3 = As[ty * 4 + 3][k];
            acc[0][0] += a0 * b.x; acc[0][1] += a0 * b.y; acc[0][2] += a0 * b.z; acc[0][3] += a0 * b.w;
            acc[1][0] += a1 * b.x; acc[1][1] += a1 * b.y; acc[1][2] += a1 * b.z; acc[1][3] += a1 * b.w;
            acc[2][0] += a2 * b.x; acc[2][1] += a2 * b.y; acc[2][2] += a2 * b.z; acc[2][3] += a2 * b.w;
            acc[3][0] += a3 * b.x; acc[3][1] += a3 * b.y; acc[3][2] += a3 * b.z; acc[3][3] += a3 * b.w;
        }
    }

    const float alpha = (MODE == 1) ? alphap[0] : 0.f;
#pragma unroll
    for (int i = 0; i < 4; ++i) {
        int vr = row0 + ty * 4 + i;
        if (vr >= N) continue;
        float dg = (MODE == 2) ? 1.f : fmaxf(deg[vr], 1.f);
#pragma unroll
        for (int j = 0; j < 4; ++j) {
            int col = tx * 4 + j;
            if (MODE == 0) {
                OUT[(size_t)vr * 64 + col] = fmaxf(acc[i][j] / dg, 0.f);
            } else if (MODE == 1) {
                OUT[(size_t)vr * 64 + col] =
                    X[(size_t)vr * 64 + col] + alpha * (acc[i][j] / dg + bias[col]);
            } else {
                if (col < 32) OUT[(size_t)vr * 32 + col] = acc[i][j] + bias[col];
            }
        }
    }
}

extern "C" void kernel_launch(void* const* d_in, const int* in_sizes, int n_in,
                              void* d_out, int out_size, void* d_ws, size_t ws_size,
                              hipStream_t stream) {
    const float* x      = (const float*)d_in[0];
    const int*   ei     = (const int*)d_in[1];   // [2][E]: src then dst
    const int*   et     = (const int*)d_in[2];
    const float* ew     = (const float*)d_in[3];
    const float* W1     = (const float*)d_in[4];   // [4][64][64] == [256][64]
    const float* W01    = (const float*)d_in[5];
    const float* alpha1 = (const float*)d_in[6];
    const float* projW1 = (const float*)d_in[7];
    const float* projb1 = (const float*)d_in[8];
    const float* W2     = (const float*)d_in[9];
    const float* W02    = (const float*)d_in[10];
    const float* alpha2 = (const float*)d_in[11];
    const float* projW2 = (const float*)d_in[12];
    const float* projb2 = (const float*)d_in[13];
    const float* outW   = (const float*)d_in[14];
    const float* outb   = (const float*)d_in[15];
    const int N = in_sizes[0] / 64;
    const int E = in_sizes[2];

    // workspace layout (floats): deg[N] | aggR[N*256] | h[N*64] | g[N*64]  (~77 MB)
    float* ws   = (float*)d_ws;
    float* deg  = ws;
    float* aggR = ws + (size_t)N;        // also reused as plain agg [N*64]
    float* hbuf = ws + (size_t)N * 257;
    float* gbuf = ws + (size_t)N * 321;

    const int scatterBlocks = (E + 3) / 4;
    const int gemmBlocks = (N + 63) / 64;
    const int degBlocks = (E + 255) / 256;

    hipMemsetAsync(deg, 0, (size_t)N * 4, stream);
    hipMemsetAsync(aggR, 0, (size_t)N * 256 * 4, stream);
    deg_count<<<degBlocks, 256, 0, stream>>>(ei, deg, E);

    // layer 1: RGCN
    scatter_rel<<<scatterBlocks, 256, 0, stream>>>(x, ei, et, ew, aggR, E);
    node_gemm<0><<<gemmBlocks, 256, 0, stream>>>(x, aggR, W01, W1, nullptr, nullptr, deg, hbuf, N);

    // layer 1: GroupEnhance
    hipMemsetAsync(aggR, 0, (size_t)N * 64 * 4, stream);
    scatter_plain<<<scatterBlocks, 256, 0, stream>>>(hbuf, ei, ew, aggR, E);
    node_gemm<1><<<gemmBlocks, 256, 0, stream>>>(hbuf, aggR, projW1, nullptr, projb1, alpha1, deg, gbuf, N);

    // layer 2: RGCN
    hipMemsetAsync(aggR, 0, (size_t)N * 256 * 4, stream);
    scatter_rel<<<scatterBlocks, 256, 0, stream>>>(gbuf, ei, et, ew, aggR, E);
    node_gemm<0><<<gemmBlocks, 256, 0, stream>>>(gbuf, aggR, W02, W2, nullptr, nullptr, deg, hbuf, N);

    // layer 2: GroupEnhance
    hipMemsetAsync(aggR, 0, (size_t)N * 64 * 4, stream);
    scatter_plain<<<scatterBlocks, 256, 0, stream>>>(hbuf, ei, ew, aggR, E);
    node_gemm<1><<<gemmBlocks, 256, 0, stream>>>(hbuf, aggR, projW2, nullptr, projb2, alpha2, deg, gbuf, N);

    // output head
    node_gemm<2><<<gemmBlocks, 256, 0, stream>>>(gbuf, nullptr, outW, nullptr, outb, nullptr, deg, (float*)d_out, N);
}

// Round 2
// 594.729 us; speedup vs baseline: 1.9191x; 1.9191x over previous
//
#include <hip/hip_runtime.h>

// ---------------------------------------------------------------------------
// MR_GNN: 2x (RGCN + GroupEnhance) + linear head.
// R1 -> R2: replace atomic scatters (250 MB atomic writes/pass, 24% HBM) with
// a dst-CSR built once per call + per-node register-accumulated gathers.
//   agg[v] = sum_r (sum_{e:r,dst=v} w_e x[src_e]) @ W[r]
// ---------------------------------------------------------------------------

__global__ void hist_dst(const int* __restrict__ ei, int* __restrict__ counts, int E) {
    int e = blockIdx.x * blockDim.x + threadIdx.x;
    if (e < E) atomicAdd(&counts[ei[E + e]], 1);
}

// block-wise exclusive scan: 256 threads x 4 items = 1024 elements/block
__global__ __launch_bounds__(256) void scan_block(const int* __restrict__ in,
                                                  int* __restrict__ out,
                                                  int* __restrict__ bsum, int N) {
    __shared__ int lds[8];
    int base = blockIdx.x * 1024;
    int tid = threadIdx.x;
    int v[4];
    int s = 0;
#pragma unroll
    for (int j = 0; j < 4; ++j) {
        int i = base + tid * 4 + j;
        v[j] = (i < N) ? in[i] : 0;
        s += v[j];
    }
    int lane = tid & 63;
    int wid = tid >> 6;
    int ws = s;
#pragma unroll
    for (int off = 1; off < 64; off <<= 1) {
        int t = __shfl_up(ws, off);
        if (lane >= off) ws += t;
    }
    if (lane == 63) lds[wid] = ws;
    __syncthreads();
    if (tid == 0) {
        int a = 0;
        for (int w = 0; w < 4; ++w) { int t = lds[w]; lds[w] = a; a += t; }
        lds[4] = a;
    }
    __syncthreads();
    int excl = lds[wid] + ws - s;
#pragma unroll
    for (int j = 0; j < 4; ++j) {
        int i = base + tid * 4 + j;
        if (i < N) out[i] = excl;
        excl += v[j];
    }
    if (tid == 0) bsum[blockIdx.x] = lds[4];
}

// single-block Hillis-Steele scan of block sums (nb <= 1024)
__global__ __launch_bounds__(1024) void scan_tops(int* __restrict__ bsum, int nb) {
    __shared__ int lds[1024];
    int tid = threadIdx.x;
    int v = (tid < nb) ? bsum[tid] : 0;
    lds[tid] = v;
    __syncthreads();
    int acc = v;
    for (int off = 1; off < 1024; off <<= 1) {
        int t = (tid >= off) ? lds[tid - off] : 0;
        __syncthreads();
        acc += t;
        lds[tid] = acc;
        __syncthreads();
    }
    if (tid < nb) bsum[tid] = acc - v;  // exclusive
}

__global__ void scan_add(int* __restrict__ rp, const int* __restrict__ bsum, int N, int E) {
    int i = blockIdx.x * 256 + threadIdx.x;
    if (i < N) rp[i] += bsum[i >> 10];
    if (i == 0) rp[N] = E;
}

// next[] must be a copy of row_ptr[0..N-1] on entry (memcpyAsync d2d)
__global__ void csr_fill(const int* __restrict__ ei, const int* __restrict__ et,
                         const float* __restrict__ ew, int* __restrict__ next,
                         int* __restrict__ csr_ps, float* __restrict__ csr_w, int E) {
    int e = blockIdx.x * 256 + threadIdx.x;
    if (e >= E) return;
    int d = ei[E + e];
    int pos = atomicAdd(&next[d], 1);
    csr_ps[pos] = (et[e] << 20) | ei[e];  // type in high bits, src in low 20
    csr_w[pos] = ew[e];
}

// one wave per node, lane = feature; 4 relation accumulators in registers
__global__ __launch_bounds__(256) void gather_rel(
    const float* __restrict__ X, const int* __restrict__ rp,
    const int* __restrict__ csr_ps, const float* __restrict__ csr_w,
    float* __restrict__ aggR, int N) {
    int node = blockIdx.x * 4 + (threadIdx.x >> 6);
    if (node >= N) return;
    int lane = threadIdx.x & 63;
    int beg = rp[node], end = rp[node + 1];
    float a0 = 0, a1 = 0, a2 = 0, a3 = 0;
    int i = beg;
    for (; i + 1 < end; i += 2) {  // 2-deep pipeline: two independent gather chains
        int ps0 = csr_ps[i], ps1 = csr_ps[i + 1];
        float w0 = csr_w[i], w1 = csr_w[i + 1];
        float x0 = X[(size_t)(ps0 & 0xFFFFF) * 64 + lane];
        float x1 = X[(size_t)(ps1 & 0xFFFFF) * 64 + lane];
        float v0 = w0 * x0, v1 = w1 * x1;
        int r0 = ps0 >> 20, r1 = ps1 >> 20;
        if (r0 == 0) a0 += v0; else if (r0 == 1) a1 += v0; else if (r0 == 2) a2 += v0; else a3 += v0;
        if (r1 == 0) a0 += v1; else if (r1 == 1) a1 += v1; else if (r1 == 2) a2 += v1; else a3 += v1;
    }
    if (i < end) {
        int ps = csr_ps[i];
        float v = csr_w[i] * X[(size_t)(ps & 0xFFFFF) * 64 + lane];
        int r = ps >> 20;
        if (r == 0) a0 += v; else if (r == 1) a1 += v; else if (r == 2) a2 += v; else a3 += v;
    }
    size_t o = (size_t)node * 256 + lane;
    aggR[o] = a0; aggR[o + 64] = a1; aggR[o + 128] = a2; aggR[o + 192] = a3;
}

__global__ __launch_bounds__(256) void gather_plain(
    const float* __restrict__ H, const int* __restrict__ rp,
    const int* __restrict__ csr_ps, const float* __restrict__ csr_w,
    float* __restrict__ agg, int N) {
    int node = blockIdx.x * 4 + (threadIdx.x >> 6);
    if (node >= N) return;
    int lane = threadIdx.x & 63;
    int beg = rp[node], end = rp[node + 1];
    float a = 0;
    int i = beg;
    for (; i + 1 < end; i += 2) {
        int ps0 = csr_ps[i], ps1 = csr_ps[i + 1];
        float w0 = csr_w[i], w1 = csr_w[i + 1];
        a += w0 * H[(size_t)(ps0 & 0xFFFFF) * 64 + lane];
        a += w1 * H[(size_t)(ps1 & 0xFFFFF) * 64 + lane];
    }
    if (i < end) a += csr_w[i] * H[(size_t)(csr_ps[i] & 0xFFFFF) * 64 + lane];
    agg[(size_t)node * 64 + lane] = a;
}

// ---------------------------------------------------------------------------
// Node-side tiled GEMM (unchanged from R1 except deg comes from row_ptr).
// MODE 0 (rgcn):  OUT = relu((X@B0 + AGG@B1) / deg)        OUT: N x 64
// MODE 1 (group): OUT = X + alpha*((AGG@B0)/deg + bias)    OUT: N x 64
// MODE 2 (head):  OUT = X@B0 + bias                        OUT: N x 32
// ---------------------------------------------------------------------------
template <int MODE>
__global__ __launch_bounds__(256) void node_gemm(
    const float* __restrict__ X, const float* __restrict__ AGG,
    const float* __restrict__ B0, const float* __restrict__ B1,
    const float* __restrict__ bias, const float* __restrict__ alphap,
    const int* __restrict__ rp, float* __restrict__ OUT, int N) {
    __shared__ float As[64][68];
    __shared__ float Bs[64][64];
    const int tid = threadIdx.x;
    const int tx = tid & 15, ty = tid >> 4;
    const int row0 = blockIdx.x * 64;
    float acc[4][4] = {};

    const int nchunks = (MODE == 0) ? 5 : 1;
    for (int c = 0; c < nchunks; ++c) {
        const float* A;
        int lda;
        const float* B;
        int ldb, bcols;
        if (MODE == 0) {
            if (c == 0) { A = X; lda = 64; B = B0; }
            else        { A = AGG + (c - 1) * 64; lda = 256; B = B1 + (size_t)(c - 1) * 64 * 64; }
            ldb = 64; bcols = 64;
        } else if (MODE == 1) {
            A = AGG; lda = 64; B = B0; ldb = 64; bcols = 64;
        } else {
            A = X; lda = 64; B = B0; ldb = 32; bcols = 32;
        }
        if (c) __syncthreads();
#pragma unroll
        for (int q = 0; q < 4; ++q) {
            int f = q * 256 + tid;
            int r = f >> 4;
            int c4 = (f & 15) << 2;
            float4 v = make_float4(0.f, 0.f, 0.f, 0.f);
            int vr = row0 + r;
            if (vr < N) v = *reinterpret_cast<const float4*>(A + (size_t)vr * lda + c4);
            *reinterpret_cast<float4*>(&As[r][c4]) = v;
            float4 bv = make_float4(0.f, 0.f, 0.f, 0.f);
            if (c4 < bcols) bv = *reinterpret_cast<const float4*>(B + (size_t)r * ldb + c4);
            *reinterpret_cast<float4*>(&Bs[r][c4]) = bv;
        }
        __syncthreads();
#pragma unroll 8
        for (int k = 0; k < 64; ++k) {
            float4 b = *reinterpret_cast<const float4*>(&Bs[k][tx * 4]);
            float a0 = As[ty * 4 + 0][k];
            float a1 = As[ty * 4 + 1][k];
            float a2 = As[ty * 4 + 2][k];
            float a3 = As[ty * 4 + 3][k];
            acc[0][0] += a0 * b.x; acc[0][1] += a0 * b.y; acc[0][2] += a0 * b.z; acc[0][3] += a0 * b.w;
            acc[1][0] += a1 * b.x; acc[1][1] += a1 * b.y; acc[1][2] += a1 * b.z; acc[1][3] += a1 * b.w;
            acc[2][0] += a2 * b.x; acc[2][1] += a2 * b.y; acc[2][2] += a2 * b.z; acc[2][3] += a2 * b.w;
            acc[3][0] += a3 * b.x; acc[3][1] += a3 * b.y; acc[3][2] += a3 * b.z; acc[3][3] += a3 * b.w;
        }
    }

    const float alpha = (MODE == 1) ? alphap[0] : 0.f;
#pragma unroll
    for (int i = 0; i < 4; ++i) {
        int vr = row0 + ty * 4 + i;
        if (vr >= N) continue;
        float dg = 1.f;
        if (MODE != 2) dg = fmaxf((float)(rp[vr + 1] - rp[vr]), 1.f);
#pragma unroll
        for (int j = 0; j < 4; ++j) {
            int col = tx * 4 + j;
            if (MODE == 0) {
                OUT[(size_t)vr * 64 + col] = fmaxf(acc[i][j] / dg, 0.f);
            } else if (MODE == 1) {
                OUT[(size_t)vr * 64 + col] =
                    X[(size_t)vr * 64 + col] + alpha * (acc[i][j] / dg + bias[col]);
            } else {
                if (col < 32) OUT[(size_t)vr * 32 + col] = acc[i][j] + bias[col];
            }
        }
    }
}

extern "C" void kernel_launch(void* const* d_in, const int* in_sizes, int n_in,
                              void* d_out, int out_size, void* d_ws, size_t ws_size,
                              hipStream_t stream) {
    const float* x      = (const float*)d_in[0];
    const int*   ei     = (const int*)d_in[1];
    const int*   et     = (const int*)d_in[2];
    const float* ew     = (const float*)d_in[3];
    const float* W1     = (const float*)d_in[4];
    const float* W01    = (const float*)d_in[5];
    const float* alpha1 = (const float*)d_in[6];
    const float* projW1 = (const float*)d_in[7];
    const float* projb1 = (const float*)d_in[8];
    const float* W2     = (const float*)d_in[9];
    const float* W02    = (const float*)d_in[10];
    const float* alpha2 = (const float*)d_in[11];
    const float* projW2 = (const float*)d_in[12];
    const float* projb2 = (const float*)d_in[13];
    const float* outW   = (const float*)d_in[14];
    const float* outb   = (const float*)d_in[15];
    const int N = in_sizes[0] / 64;
    const int E = in_sizes[2];

    // workspace (4-byte units):
    // counts/next[N] | row_ptr[N+1] | bsum[1024] | csr_ps[E] | csr_w[E]
    // | aggR[N*256] | h[N*64] | g[N*64]   (~86 MB)
    int*   counts = (int*)d_ws;
    int*   rp     = counts + N;
    int*   bsum   = rp + N + 1;
    int*   csr_ps = bsum + 1024;
    float* csr_w  = (float*)(csr_ps + E);
    float* aggR   = csr_w + E;
    float* hbuf   = aggR + (size_t)N * 256;
    float* gbuf   = hbuf + (size_t)N * 64;

    const int nb = (N + 1023) / 1024;
    const int gatherBlocks = (N + 3) / 4;
    const int gemmBlocks = (N + 63) / 64;
    const int eBlocks = (E + 255) / 256;

    // ---- CSR build (once per call) ----
    hipMemsetAsync(counts, 0, (size_t)N * 4, stream);
    hist_dst<<<eBlocks, 256, 0, stream>>>(ei, counts, E);
    scan_block<<<nb, 256, 0, stream>>>(counts, rp, bsum, N);
    scan_tops<<<1, 1024, 0, stream>>>(bsum, nb);
    scan_add<<<(N + 255) / 256, 256, 0, stream>>>(rp, bsum, N, E);
    hipMemcpyAsync(counts, rp, (size_t)N * 4, hipMemcpyDeviceToDevice, stream);  // counts -> next
    csr_fill<<<eBlocks, 256, 0, stream>>>(ei, et, ew, counts, csr_ps, csr_w, E);

    // ---- layer 1 ----
    gather_rel<<<gatherBlocks, 256, 0, stream>>>(x, rp, csr_ps, csr_w, aggR, N);
    node_gemm<0><<<gemmBlocks, 256, 0, stream>>>(x, aggR, W01, W1, nullptr, nullptr, rp, hbuf, N);
    gather_plain<<<gatherBlocks, 256, 0, stream>>>(hbuf, rp, csr_ps, csr_w, aggR, N);
    node_gemm<1><<<gemmBlocks, 256, 0, stream>>>(hbuf, aggR, projW1, nullptr, projb1, alpha1, rp, gbuf, N);

    // ---- layer 2 ----
    gather_rel<<<gatherBlocks, 256, 0, stream>>>(gbuf, rp, csr_ps, csr_w, aggR, N);
    node_gemm<0><<<gemmBlocks, 256, 0, stream>>>(gbuf, aggR, W02, W2, nullptr, nullptr, rp, hbuf, N);
    gather_plain<<<gatherBlocks, 256, 0, stream>>>(hbuf, rp, csr_ps, csr_w, aggR, N);
    node_gemm<1><<<gemmBlocks, 256, 0, stream>>>(hbuf, aggR, projW2, nullptr, projb2, alpha2, rp, gbuf, N);

    // ---- head ----
    node_gemm<2><<<gemmBlocks, 256, 0, stream>>>(gbuf, nullptr, outW, nullptr, outb, nullptr, rp, (float*)d_out, N);
}

// Round 3
// 503.378 us; speedup vs baseline: 2.2673x; 1.1815x over previous
//
#include <hip/hip_runtime.h>

// ---------------------------------------------------------------------------
// MR_GNN: 2x (RGCN + GroupEnhance) + linear head.
// R2 -> R3: (a) relation-partitioned CSR (4N segments) kills the per-edge
// relation select chain; (b) edge-parallel gathers: 16 lanes x float4 per
// edge row, 4 edges per wave per load instruction, 2x unroll (8 gathers in
// flight), cross-quarter shfl_xor reduction per node.
// ---------------------------------------------------------------------------

__global__ void hist_dst(const int* __restrict__ ei, const int* __restrict__ et,
                         int* __restrict__ counts, int E) {
    int e = blockIdx.x * blockDim.x + threadIdx.x;
    if (e < E) atomicAdd(&counts[ei[E + e] * 4 + et[e]], 1);
}

// block-wise exclusive scan: 256 threads x 4 items = 1024 elements/block
__global__ __launch_bounds__(256) void scan_block(const int* __restrict__ in,
                                                  int* __restrict__ out,
                                                  int* __restrict__ bsum, int M) {
    __shared__ int lds[8];
    int base = blockIdx.x * 1024;
    int tid = threadIdx.x;
    int v[4];
    int s = 0;
#pragma unroll
    for (int j = 0; j < 4; ++j) {
        int i = base + tid * 4 + j;
        v[j] = (i < M) ? in[i] : 0;
        s += v[j];
    }
    int lane = tid & 63;
    int wid = tid >> 6;
    int ws = s;
#pragma unroll
    for (int off = 1; off < 64; off <<= 1) {
        int t = __shfl_up(ws, off);
        if (lane >= off) ws += t;
    }
    if (lane == 63) lds[wid] = ws;
    __syncthreads();
    if (tid == 0) {
        int a = 0;
        for (int w = 0; w < 4; ++w) { int t = lds[w]; lds[w] = a; a += t; }
        lds[4] = a;
    }
    __syncthreads();
    int excl = lds[wid] + ws - s;
#pragma unroll
    for (int j = 0; j < 4; ++j) {
        int i = base + tid * 4 + j;
        if (i < M) out[i] = excl;
        excl += v[j];
    }
    if (tid == 0) bsum[blockIdx.x] = lds[4];
}

// single-block Hillis-Steele scan of block sums (nb <= 1024)
__global__ __launch_bounds__(1024) void scan_tops(int* __restrict__ bsum, int nb) {
    __shared__ int lds[1024];
    int tid = threadIdx.x;
    int v = (tid < nb) ? bsum[tid] : 0;
    lds[tid] = v;
    __syncthreads();
    int acc = v;
    for (int off = 1; off < 1024; off <<= 1) {
        int t = (tid >= off) ? lds[tid - off] : 0;
        __syncthreads();
        acc += t;
        lds[tid] = acc;
        __syncthreads();
    }
    if (tid < nb) bsum[tid] = acc - v;  // exclusive
}

__global__ void scan_add(int* __restrict__ rp, const int* __restrict__ bsum, int M, int E) {
    int i = blockIdx.x * 256 + threadIdx.x;
    if (i < M) rp[i] += bsum[i >> 10];
    if (i == 0) rp[M] = E;
}

// next[] must be a copy of rp2[0..4N-1] on entry (memcpyAsync d2d)
__global__ void csr_fill(const int* __restrict__ ei, const int* __restrict__ et,
                         const float* __restrict__ ew, int* __restrict__ next,
                         int2* __restrict__ pw, int E) {
    int e = blockIdx.x * 256 + threadIdx.x;
    if (e >= E) return;
    int pos = atomicAdd(&next[ei[E + e] * 4 + et[e]], 1);
    pw[pos] = make_int2(ei[e], __float_as_int(ew[e]));
}

__device__ __forceinline__ float4 quad_reduce(float4 a) {
#pragma unroll
    for (int off = 16; off < 64; off <<= 1) {
        a.x += __shfl_xor(a.x, off);
        a.y += __shfl_xor(a.y, off);
        a.z += __shfl_xor(a.z, off);
        a.w += __shfl_xor(a.w, off);
    }
    return a;
}

// one wave per node; lane = 16*q + m: quarter q handles edges beg+q+4k,
// m indexes a float4 of the 64-feature row. 4 relation segments in sequence.
__global__ __launch_bounds__(256) void gather_rel(
    const float* __restrict__ X, const int* __restrict__ rp2,
    const int2* __restrict__ pw, float* __restrict__ aggR, int N) {
    int node = blockIdx.x * 4 + (threadIdx.x >> 6);
    if (node >= N) return;
    int lane = threadIdx.x & 63;
    int q = lane >> 4, m = lane & 15;
#pragma unroll
    for (int r = 0; r < 4; ++r) {
        int beg = rp2[node * 4 + r], end = rp2[node * 4 + r + 1];
        float4 acc = make_float4(0.f, 0.f, 0.f, 0.f);
        int i = beg + q;
        for (; i + 4 < end; i += 8) {  // two independent gathers per iter
            int2 a = pw[i];
            int2 b = pw[i + 4];
            float4 xa = *reinterpret_cast<const float4*>(X + (size_t)a.x * 64 + m * 4);
            float4 xb = *reinterpret_cast<const float4*>(X + (size_t)b.x * 64 + m * 4);
            float wa = __int_as_float(a.y), wb = __int_as_float(b.y);
            acc.x += wa * xa.x; acc.y += wa * xa.y; acc.z += wa * xa.z; acc.w += wa * xa.w;
            acc.x += wb * xb.x; acc.y += wb * xb.y; acc.z += wb * xb.z; acc.w += wb * xb.w;
        }
        if (i < end) {
            int2 a = pw[i];
            float4 xa = *reinterpret_cast<const float4*>(X + (size_t)a.x * 64 + m * 4);
            float wa = __int_as_float(a.y);
            acc.x += wa * xa.x; acc.y += wa * xa.y; acc.z += wa * xa.z; acc.w += wa * xa.w;
        }
        acc = quad_reduce(acc);
        if (q == r)
            *reinterpret_cast<float4*>(aggR + (size_t)node * 256 + r * 64 + m * 4) = acc;
    }
}

__global__ __launch_bounds__(256) void gather_plain(
    const float* __restrict__ H, const int* __restrict__ rp2,
    const int2* __restrict__ pw, float* __restrict__ agg, int N) {
    int node = blockIdx.x * 4 + (threadIdx.x >> 6);
    if (node >= N) return;
    int lane = threadIdx.x & 63;
    int q = lane >> 4, m = lane & 15;
    int beg = rp2[node * 4], end = rp2[node * 4 + 4];
    float4 acc = make_float4(0.f, 0.f, 0.f, 0.f);
    int i = beg + q;
    for (; i + 4 < end; i += 8) {
        int2 a = pw[i];
        int2 b = pw[i + 4];
        float4 xa = *reinterpret_cast<const float4*>(H + (size_t)a.x * 64 + m * 4);
        float4 xb = *reinterpret_cast<const float4*>(H + (size_t)b.x * 64 + m * 4);
        float wa = __int_as_float(a.y), wb = __int_as_float(b.y);
        acc.x += wa * xa.x; acc.y += wa * xa.y; acc.z += wa * xa.z; acc.w += wa * xa.w;
        acc.x += wb * xb.x; acc.y += wb * xb.y; acc.z += wb * xb.z; acc.w += wb * xb.w;
    }
    if (i < end) {
        int2 a = pw[i];
        float4 xa = *reinterpret_cast<const float4*>(H + (size_t)a.x * 64 + m * 4);
        float wa = __int_as_float(a.y);
        acc.x += wa * xa.x; acc.y += wa * xa.y; acc.z += wa * xa.z; acc.w += wa * xa.w;
    }
    acc = quad_reduce(acc);
    if (q == 0)
        *reinterpret_cast<float4*>(agg + (size_t)node * 64 + m * 4) = acc;
}

// ---------------------------------------------------------------------------
// Node-side tiled GEMM (deg from rp2 row bounds).
// MODE 0 (rgcn):  OUT = relu((X@B0 + AGG@B1) / deg)        OUT: N x 64
// MODE 1 (group): OUT = X + alpha*((AGG@B0)/deg + bias)    OUT: N x 64
// MODE 2 (head):  OUT = X@B0 + bias                        OUT: N x 32
// ---------------------------------------------------------------------------
template <int MODE>
__global__ __launch_bounds__(256) void node_gemm(
    const float* __restrict__ X, const float* __restrict__ AGG,
    const float* __restrict__ B0, const float* __restrict__ B1,
    const float* __restrict__ bias, const float* __restrict__ alphap,
    const int* __restrict__ rp2, float* __restrict__ OUT, int N) {
    __shared__ float As[64][68];
    __shared__ float Bs[64][64];
    const int tid = threadIdx.x;
    const int tx = tid & 15, ty = tid >> 4;
    const int row0 = blockIdx.x * 64;
    float acc[4][4] = {};

    const int nchunks = (MODE == 0) ? 5 : 1;
    for (int c = 0; c < nchunks; ++c) {
        const float* A;
        int lda;
        const float* B;
        int ldb, bcols;
        if (MODE == 0) {
            if (c == 0) { A = X; lda = 64; B = B0; }
            else        { A = AGG + (c - 1) * 64; lda = 256; B = B1 + (size_t)(c - 1) * 64 * 64; }
            ldb = 64; bcols = 64;
        } else if (MODE == 1) {
            A = AGG; lda = 64; B = B0; ldb = 64; bcols = 64;
        } else {
            A = X; lda = 64; B = B0; ldb = 32; bcols = 32;
        }
        if (c) __syncthreads();
#pragma unroll
        for (int q = 0; q < 4; ++q) {
            int f = q * 256 + tid;
            int r = f >> 4;
            int c4 = (f & 15) << 2;
            float4 v = make_float4(0.f, 0.f, 0.f, 0.f);
            int vr = row0 + r;
            if (vr < N) v = *reinterpret_cast<const float4*>(A + (size_t)vr * lda + c4);
            *reinterpret_cast<float4*>(&As[r][c4]) = v;
            float4 bv = make_float4(0.f, 0.f, 0.f, 0.f);
            if (c4 < bcols) bv = *reinterpret_cast<const float4*>(B + (size_t)r * ldb + c4);
            *reinterpret_cast<float4*>(&Bs[r][c4]) = bv;
        }
        __syncthreads();
#pragma unroll 8
        for (int k = 0; k < 64; ++k) {
            float4 b = *reinterpret_cast<const float4*>(&Bs[k][tx * 4]);
            float a0 = As[ty * 4 + 0][k];
            float a1 = As[ty * 4 + 1][k];
            float a2 = As[ty * 4 + 2][k];
            float a3 = As[ty * 4 + 3][k];
            acc[0][0] += a0 * b.x; acc[0][1] += a0 * b.y; acc[0][2] += a0 * b.z; acc[0][3] += a0 * b.w;
            acc[1][0] += a1 * b.x; acc[1][1] += a1 * b.y; acc[1][2] += a1 * b.z; acc[1][3] += a1 * b.w;
            acc[2][0] += a2 * b.x; acc[2][1] += a2 * b.y; acc[2][2] += a2 * b.z; acc[2][3] += a2 * b.w;
            acc[3][0] += a3 * b.x; acc[3][1] += a3 * b.y; acc[3][2] += a3 * b.z; acc[3][3] += a3 * b.w;
        }
    }

    const float alpha = (MODE == 1) ? alphap[0] : 0.f;
#pragma unroll
    for (int i = 0; i < 4; ++i) {
        int vr = row0 + ty * 4 + i;
        if (vr >= N) continue;
        float dg = 1.f;
        if (MODE != 2) dg = fmaxf((float)(rp2[vr * 4 + 4] - rp2[vr * 4]), 1.f);
#pragma unroll
        for (int j = 0; j < 4; ++j) {
            int col = tx * 4 + j;
            if (MODE == 0) {
                OUT[(size_t)vr * 64 + col] = fmaxf(acc[i][j] / dg, 0.f);
            } else if (MODE == 1) {
                OUT[(size_t)vr * 64 + col] =
                    X[(size_t)vr * 64 + col] + alpha * (acc[i][j] / dg + bias[col]);
            } else {
                if (col < 32) OUT[(size_t)vr * 32 + col] = acc[i][j] + bias[col];
            }
        }
    }
}

extern "C" void kernel_launch(void* const* d_in, const int* in_sizes, int n_in,
                              void* d_out, int out_size, void* d_ws, size_t ws_size,
                              hipStream_t stream) {
    const float* x      = (const float*)d_in[0];
    const int*   ei     = (const int*)d_in[1];
    const int*   et     = (const int*)d_in[2];
    const float* ew     = (const float*)d_in[3];
    const float* W1     = (const float*)d_in[4];
    const float* W01    = (const float*)d_in[5];
    const float* alpha1 = (const float*)d_in[6];
    const float* projW1 = (const float*)d_in[7];
    const float* projb1 = (const float*)d_in[8];
    const float* W2     = (const float*)d_in[9];
    const float* W02    = (const float*)d_in[10];
    const float* alpha2 = (const float*)d_in[11];
    const float* projW2 = (const float*)d_in[12];
    const float* projb2 = (const float*)d_in[13];
    const float* outW   = (const float*)d_in[14];
    const float* outb   = (const float*)d_in[15];
    const int N = in_sizes[0] / 64;
    const int E = in_sizes[2];
    const int M = 4 * N;  // (dst, rel) segments

    // workspace (4-byte units):
    // counts4/next4[M] | rp2[M+1] | bsum[1024] | pw int2[E] | aggR[N*256]
    // | h[N*64] | g[N*64]
    int*   counts4 = (int*)d_ws;
    int*   rp2     = counts4 + M;
    int*   bsum    = rp2 + M + 1;
    int2*  pw      = (int2*)(bsum + 1024);
    float* aggR    = (float*)(pw + E);
    float* hbuf    = aggR + (size_t)N * 256;
    float* gbuf    = hbuf + (size_t)N * 64;

    const int nb = (M + 1023) / 1024;
    const int gatherBlocks = (N + 3) / 4;
    const int gemmBlocks = (N + 63) / 64;
    const int eBlocks = (E + 255) / 256;

    // ---- CSR build (once per call) ----
    hipMemsetAsync(counts4, 0, (size_t)M * 4, stream);
    hist_dst<<<eBlocks, 256, 0, stream>>>(ei, et, counts4, E);
    scan_block<<<nb, 256, 0, stream>>>(counts4, rp2, bsum, M);
    scan_tops<<<1, 1024, 0, stream>>>(bsum, nb);
    scan_add<<<(M + 255) / 256, 256, 0, stream>>>(rp2, bsum, M, E);
    hipMemcpyAsync(counts4, rp2, (size_t)M * 4, hipMemcpyDeviceToDevice, stream);
    csr_fill<<<eBlocks, 256, 0, stream>>>(ei, et, ew, counts4, pw, E);

    // ---- layer 1 ----
    gather_rel<<<gatherBlocks, 256, 0, stream>>>(x, rp2, pw, aggR, N);
    node_gemm<0><<<gemmBlocks, 256, 0, stream>>>(x, aggR, W01, W1, nullptr, nullptr, rp2, hbuf, N);
    gather_plain<<<gatherBlocks, 256, 0, stream>>>(hbuf, rp2, pw, aggR, N);
    node_gemm<1><<<gemmBlocks, 256, 0, stream>>>(hbuf, aggR, projW1, nullptr, projb1, alpha1, rp2, gbuf, N);

    // ---- layer 2 ----
    gather_rel<<<gatherBlocks, 256, 0, stream>>>(gbuf, rp2, pw, aggR, N);
    node_gemm<0><<<gemmBlocks, 256, 0, stream>>>(gbuf, aggR, W02, W2, nullptr, nullptr, rp2, hbuf, N);
    gather_plain<<<gatherBlocks, 256, 0, stream>>>(hbuf, rp2, pw, aggR, N);
    node_gemm<1><<<gemmBlocks, 256, 0, stream>>>(hbuf, aggR, projW2, nullptr, projb2, alpha2, rp2, gbuf, N);

    // ---- head ----
    node_gemm<2><<<gemmBlocks, 256, 0, stream>>>(gbuf, nullptr, outW, nullptr, outb, nullptr, rp2, (float*)d_out, N);
}